// Round 4
// baseline (385.092 us; speedup 1.0000x reference)
//
#include <hip/hip_runtime.h>
#include <hip/hip_cooperative_groups.h>
#include <math.h>

#define HID 1024
#define P4  4096

namespace cg = cooperative_groups;

struct Params {
    const float* input; const float* eq;
    const float* W1; const float* b1; const float* W2; const float* b2;
    const float* qx[4]; const float* wa[4]; const float* ba[4];
    const float* wb[4]; const float* bb[4];
    float* Sg;    // ws: 256 floats  (S_f[64] x 4)
    float* w2r;   // ws: 1024 floats
    float* b2r;   // ws: 1 float
    float* out;   // 32768 floats
};

__device__ __forceinline__ float fast_tanh(float x) {
    // tanh(x) = sign(x) * (1 - e) / (1 + e),  e = exp(-2|x|) in (0,1]
    float e = __expf(-2.0f * fabsf(x));
    float t = (1.0f - e) * __builtin_amdgcn_rcpf(1.0f + e);
    return copysignf(t, x);
}

// One cooperative kernel, 1024 blocks x 256 threads (4 blocks/CU co-resident).
// Phase A: blocks 0..3 compute factor MLPs -> Sg; ALL blocks prefetch their
//          W2 row (16KB) into 16 registers (latency hidden across grid.sync).
// Phase B: each block rebuilds rhs[4096] in LDS from Sg (cheap: 98K FLOP),
//          dots with its W2 row -> w2r[bid]. Block 0 also b2r = b2.rhs.
// Phase C: 32 rows/block: out[n] = b2r + sum_h tanh(x.W1[:,h]+b1[h))*w2r[h],
//          W1^T/b1 packed float4 + w2r staged in LDS (broadcast reads).
__global__ __launch_bounds__(256, 4) void k_fused(Params p)
{
    union SharedU {
        struct { float2 qy[64]; float wh[128]; } a;                      // 1.5 KB
        struct { float S[256]; float rhs[P4]; float red[256]; } b;       // 18 KB
        struct { float4 wpack[HID]; float w2rs[HID]; float part[8][32]; } c; // 21 KB
    };
    __shared__ SharedU sm;

    cg::grid_group grid = cg::this_grid();
    const int bid = blockIdx.x;
    const int t   = threadIdx.x;

    // ---- Phase A0: prefetch W2 row `bid` into registers (consumed in B) ----
    float4 wreg0, wreg1, wreg2, wreg3;
    {
        const float4* w4 = (const float4*)(p.W2 + (size_t)bid * P4);
        wreg0 = w4[t];
        wreg1 = w4[t + 256];
        wreg2 = w4[t + 512];
        wreg3 = w4[t + 768];
    }

    // ---- Phase A1: factor MLPs on blocks 0..3 (factor f = bid) ----
    if (bid < 4) {
        const float* qx = p.qx[bid]; const float* wa = p.wa[bid];
        const float* ba = p.ba[bid]; const float* wb = p.wb[bid];
        const float* bb = p.bb[bid];

        float ysum = 0.f;
        if (t < 64) {   // wave 0: y[p] = eq * sin(pi*qx[p])
            float qv = qx[t];
            float yv = p.eq[0] * sinf((float)M_PI * qv);
            sm.a.qy[t] = make_float2(qv, yv);
            ysum = yv;
            #pragma unroll
            for (int off = 32; off; off >>= 1) ysum += __shfl_xor(ysum, off);
        }
        __syncthreads();
        if (t < 128) {  // hidden unit h = t
            float w = wa[t], c0 = ba[t], a = 0.f;
            #pragma unroll 8
            for (int q = 0; q < 64; ++q) {
                float2 qy = sm.a.qy[q];             // LDS broadcast
                a += qy.y * fast_tanh(fmaf(qy.x, w, c0));
            }
            sm.a.wh[t] = a;
        }
        __syncthreads();
        if (t < 64) {   // output j = t: S_f[j]
            float acc = bb[t] * ysum;
            #pragma unroll 8
            for (int h = 0; h < 128; ++h)
                acc = fmaf(sm.a.wh[h], wb[h * 64 + t], acc);   // wb coalesced
            p.Sg[bid * 64 + t] = acc;
        }
    }

    grid.sync();

    // ---- Phase B: rhs in LDS, then w2r[bid] = W2row . rhs ----
    sm.b.S[t] = p.Sg[t];                // 256 floats
    __syncthreads();

    float b2local = 0.f;
    #pragma unroll
    for (int k = 0; k < 16; ++k) {
        const int i = t + 256 * k;
        const int m  = i & 7;
        const int fq = (i >> 3) & 7;
        const int d  = (i >> 6) & 7;
        const int b  = (i >> 9) & 7;
        float acc = 0.f;
        #pragma unroll
        for (int x = 0; x < 8; ++x)
            acc += sm.b.S[b * 8 + x]       * sm.b.S[64 + d * 8 + x]
                 * sm.b.S[128 + fq * 8 + x] * sm.b.S[192 + m * 8 + x];
        sm.b.rhs[i] = acc;
        if (bid == 0) b2local = fmaf(p.b2[i], acc, b2local);
    }
    __syncthreads();

    {
        const float4* r4 = (const float4*)sm.b.rhs;
        float4 a0 = r4[t], a1 = r4[t + 256], a2 = r4[t + 512], a3 = r4[t + 768];
        float acc = wreg0.x * a0.x + wreg0.y * a0.y + wreg0.z * a0.z + wreg0.w * a0.w
                  + wreg1.x * a1.x + wreg1.y * a1.y + wreg1.z * a1.z + wreg1.w * a1.w
                  + wreg2.x * a2.x + wreg2.y * a2.y + wreg2.z * a2.z + wreg2.w * a2.w
                  + wreg3.x * a3.x + wreg3.y * a3.y + wreg3.z * a3.z + wreg3.w * a3.w;
        sm.b.red[t] = acc;
    }
    __syncthreads();
    if (t < 64) {
        float v = sm.b.red[t] + sm.b.red[t + 64] + sm.b.red[t + 128] + sm.b.red[t + 192];
        #pragma unroll
        for (int off = 32; off; off >>= 1) v += __shfl_xor(v, off);
        if (t == 0) p.w2r[bid] = v;
    }
    if (bid == 0) {   // block-uniform branch: safe to barrier inside
        __syncthreads();
        sm.b.red[t] = b2local;
        __syncthreads();
        if (t < 64) {
            float v = sm.b.red[t] + sm.b.red[t + 64] + sm.b.red[t + 128] + sm.b.red[t + 192];
            #pragma unroll
            for (int off = 32; off; off >>= 1) v += __shfl_xor(v, off);
            if (t == 0) p.b2r[0] = v;
        }
    }

    grid.sync();

    // ---- Phase C: 32 output rows per block ----
    #pragma unroll
    for (int h = t; h < HID; h += 256) {
        sm.c.wpack[h] = make_float4(p.W1[h], p.W1[HID + h], p.W1[2 * HID + h], p.b1[h]);
        sm.c.w2rs[h]  = p.w2r[h];
    }
    __syncthreads();

    const int r = t & 31;          // row within block
    const int c = t >> 5;          // h-chunk 0..7 (128 h each)
    const int row = bid * 32 + r;
    const float* x = p.input + (size_t)row * 3;
    const float x0 = x[0], x1 = x[1], x2 = x[2];

    float acc = 0.f;
    const int h0 = c * 128;
    #pragma unroll 8
    for (int h = h0; h < h0 + 128; ++h) {
        float4 wp = sm.c.wpack[h];        // 2 addrs/wave -> free broadcast
        float pre = fmaf(x0, wp.x, fmaf(x1, wp.y, fmaf(x2, wp.z, wp.w)));
        acc = fmaf(fast_tanh(pre), sm.c.w2rs[h], acc);
    }
    sm.c.part[c][r] = acc;
    __syncthreads();
    if (t < 32) {
        float v = p.b2r[0];
        #pragma unroll
        for (int cc = 0; cc < 8; ++cc) v += sm.c.part[cc][t];
        p.out[bid * 32 + t] = v;
    }
}

// ---------------------------------------------------------------------------
extern "C" void kernel_launch(void* const* d_in, const int* in_sizes, int n_in,
                              void* d_out, int out_size, void* d_ws, size_t ws_size,
                              hipStream_t stream)
{
    Params p;
    p.input = (const float*)d_in[0];
    p.eq    = (const float*)d_in[1];
    p.W1    = (const float*)d_in[2];
    p.b1    = (const float*)d_in[3];
    p.W2    = (const float*)d_in[4];
    p.b2    = (const float*)d_in[5];
    for (int i = 0; i < 4; ++i) {
        p.qx[i] = (const float*)d_in[6 + 5 * i + 0];
        p.wa[i] = (const float*)d_in[6 + 5 * i + 1];
        p.ba[i] = (const float*)d_in[6 + 5 * i + 2];
        p.wb[i] = (const float*)d_in[6 + 5 * i + 3];
        p.bb[i] = (const float*)d_in[6 + 5 * i + 4];
    }
    float* ws = (float*)d_ws;
    p.Sg  = ws;          // 256
    p.w2r = ws + 256;    // 1024
    p.b2r = ws + 1280;   // 1
    p.out = (float*)d_out;

    void* args[] = { &p };
    hipLaunchCooperativeKernel((const void*)k_fused, dim3(1024), dim3(256),
                               args, 0, stream);
}

// Round 5
// 142.964 us; speedup vs baseline: 2.6936x; 2.6936x over previous
//
#include <hip/hip_runtime.h>
#include <math.h>

#define HID 1024
#define P4  4096

// ---------------------------------------------------------------------------
// Kernel 1 "front": factor MLPs (redundant per block, ~1us) -> S[4][64] ->
// rhs[4096] in LDS -> each wave dots one W2 row -> w2r[1024].
// Block 0 additionally computes b2r = b2 . rhs.
// grid = 256 blocks x 256 threads (wave f of block b owns W2 row 4b+f).
// ---------------------------------------------------------------------------
__global__ __launch_bounds__(256) void k_front(
    const float* __restrict__ eq,
    const float* __restrict__ qx0, const float* __restrict__ wa0, const float* __restrict__ ba0,
    const float* __restrict__ wb0, const float* __restrict__ bb0,
    const float* __restrict__ qx1, const float* __restrict__ wa1, const float* __restrict__ ba1,
    const float* __restrict__ wb1, const float* __restrict__ bb1,
    const float* __restrict__ qx2, const float* __restrict__ wa2, const float* __restrict__ ba2,
    const float* __restrict__ wb2, const float* __restrict__ bb2,
    const float* __restrict__ qx3, const float* __restrict__ wa3, const float* __restrict__ ba3,
    const float* __restrict__ wb3, const float* __restrict__ bb3,
    const float* __restrict__ b2, const float* __restrict__ W2,
    float* __restrict__ w2r, float* __restrict__ b2r)
{
    __shared__ float2 qy[4][64];
    __shared__ float  wh[4][128];
    __shared__ float  S[4][64];
    __shared__ float  rhs_s[P4];
    __shared__ float  red[256];

    const int t    = threadIdx.x;
    const int lane = t & 63;
    const int f    = t >> 6;   // wave-uniform factor index

    const float* qx; const float* wa; const float* ba; const float* wb; const float* bb;
    if (f == 0)      { qx = qx0; wa = wa0; ba = ba0; wb = wb0; bb = bb0; }
    else if (f == 1) { qx = qx1; wa = wa1; ba = ba1; wb = wb1; bb = bb1; }
    else if (f == 2) { qx = qx2; wa = wa2; ba = ba2; wb = wb2; bb = bb2; }
    else             { qx = qx3; wa = wa3; ba = ba3; wb = wb3; bb = bb3; }

    // stage 1: y = eq * sin(pi qx); ysum across wave
    const float qv = qx[lane];
    const float yv = eq[0] * sinf((float)M_PI * qv);
    qy[f][lane] = make_float2(qv, yv);
    float ysum = yv;
    #pragma unroll
    for (int off = 32; off; off >>= 1) ysum += __shfl_xor(ysum, off);
    __syncthreads();

    // stage 2: hidden units h=lane, h=lane+64.
    // tanh(z) = 1 - 2*rcp(exp(2z)+1); fold the 2 into prescaled weights.
    // wh[h] = sum_p y_p tanh_p = ysum - 2*sum_p y_p * r_{p,h}
    {
        const float w0 = 2.f * wa[lane],      c0 = 2.f * ba[lane];
        const float w1 = 2.f * wa[lane + 64], c1 = 2.f * ba[lane + 64];
        float a0 = 0.f, a1 = 0.f;
        #pragma unroll 8
        for (int p = 0; p < 64; ++p) {
            float2 q = qy[f][p];                               // LDS broadcast
            float r0 = __builtin_amdgcn_rcpf(__expf(fmaf(q.x, w0, c0)) + 1.f);
            float r1 = __builtin_amdgcn_rcpf(__expf(fmaf(q.x, w1, c1)) + 1.f);
            a0 = fmaf(q.y, r0, a0);
            a1 = fmaf(q.y, r1, a1);
        }
        wh[f][lane]      = ysum - 2.f * a0;
        wh[f][lane + 64] = ysum - 2.f * a1;
    }
    __syncthreads();

    // stage 3: S_f[j] = bb[j]*ysum + sum_h wh[h] * wb[h,j]
    {
        float acc = bb[lane] * ysum;
        #pragma unroll 8
        for (int h = 0; h < 128; ++h)
            acc = fmaf(wh[f][h], wb[h * 64 + lane], acc);      // wb coalesced
        S[f][lane] = acc;
    }
    __syncthreads();

    // stage B1: rhs[i] for i = t + 256k; block 0 also b2 . rhs
    float ab = 0.f;
    #pragma unroll
    for (int k = 0; k < 16; ++k) {
        const int i  = t + 256 * k;
        const int m  = i & 7;
        const int fq = (i >> 3) & 7;
        const int d  = (i >> 6) & 7;
        const int b  = (i >> 9) & 7;
        float rv = 0.f;
        #pragma unroll
        for (int x = 0; x < 8; ++x)
            rv += S[0][b * 8 + x] * S[1][d * 8 + x]
                * S[2][fq * 8 + x] * S[3][m * 8 + x];
        rhs_s[i] = rv;
        if (blockIdx.x == 0) ab = fmaf(b2[i], rv, ab);
    }
    __syncthreads();

    // stage B2: wave f dots W2 row (4*bid+f) with rhs (float4)
    {
        const int row = blockIdx.x * 4 + f;
        const float4* W4 = (const float4*)(W2 + (size_t)row * P4);
        const float4* R4 = (const float4*)rhs_s;
        float aw = 0.f;
        #pragma unroll
        for (int k = 0; k < 16; ++k) {
            const int idx = lane + 64 * k;
            float4 w = W4[idx];
            float4 r = R4[idx];
            aw += w.x * r.x + w.y * r.y + w.z * r.z + w.w * r.w;
        }
        #pragma unroll
        for (int off = 32; off; off >>= 1) aw += __shfl_xor(aw, off);
        if (lane == 0) w2r[row] = aw;
    }

    if (blockIdx.x == 0) {   // block-uniform: safe to barrier
        red[t] = ab;
        __syncthreads();
        if (t < 128) red[t] += red[t + 128];
        __syncthreads();
        if (t < 64) {
            float v = red[t] + red[t + 64];
            #pragma unroll
            for (int off = 32; off; off >>= 1) v += __shfl_xor(v, off);
            if (t == 0) b2r[0] = v;
        }
    }
}

// ---------------------------------------------------------------------------
// Kernel 2 "out": out[n] = b2r + sum_h tanh(x.W1[:,h]+b1[h]) * w2r[h]
// 1024 blocks x 256 threads; 32 rows/block (4 blocks/CU).
// Weights live in REGISTERS (thread owns 4 h-columns, prescaled by 2);
// rows staged in LDS; per-row wave shuffle-reduce.
// sum_h w2r*tanh = sum_h w2r - 2*sum_h w2r*rcp(exp(2z)+1): the constant
// sum_h w2r is hoisted out of the row loop (one wave reduce at init).
// ---------------------------------------------------------------------------
__global__ __launch_bounds__(256) void k_out(
    const float* __restrict__ input,
    const float* __restrict__ W1, const float* __restrict__ b1,
    const float* __restrict__ w2r, const float* __restrict__ b2r,
    float* __restrict__ out)
{
    __shared__ float xs[96];        // 32 rows x 3 coords
    __shared__ float part[4][32];

    const int t    = threadIdx.x;
    const int lane = t & 63;
    const int w    = t >> 6;

    if (t < 96) xs[t] = input[(size_t)blockIdx.x * 96 + t];

    const int h0 = w * 256 + lane * 4;
    float4 wa = *(const float4*)(W1 + h0);            // W1[0][h0..h0+3]
    float4 wb = *(const float4*)(W1 + HID + h0);      // W1[1][...]
    float4 wc = *(const float4*)(W1 + 2 * HID + h0);  // W1[2][...]
    float4 bb = *(const float4*)(b1 + h0);
    float4 wr = *(const float4*)(w2r + h0);
    wa.x *= 2.f; wa.y *= 2.f; wa.z *= 2.f; wa.w *= 2.f;
    wb.x *= 2.f; wb.y *= 2.f; wb.z *= 2.f; wb.w *= 2.f;
    wc.x *= 2.f; wc.y *= 2.f; wc.z *= 2.f; wc.w *= 2.f;
    bb.x *= 2.f; bb.y *= 2.f; bb.z *= 2.f; bb.w *= 2.f;

    float sw = wr.x + wr.y + wr.z + wr.w;             // sum_h w2r (wave chunk)
    #pragma unroll
    for (int off = 32; off; off >>= 1) sw += __shfl_xor(sw, off);

    __syncthreads();

    #pragma unroll 4
    for (int r = 0; r < 32; ++r) {
        const float x0 = xs[3 * r + 0];               // broadcast
        const float x1 = xs[3 * r + 1];
        const float x2 = xs[3 * r + 2];

        float acc;
        {
            float pre0 = fmaf(x2, wc.x, fmaf(x1, wb.x, fmaf(x0, wa.x, bb.x)));
            float pre1 = fmaf(x2, wc.y, fmaf(x1, wb.y, fmaf(x0, wa.y, bb.y)));
            float pre2 = fmaf(x2, wc.z, fmaf(x1, wb.z, fmaf(x0, wa.z, bb.z)));
            float pre3 = fmaf(x2, wc.w, fmaf(x1, wb.w, fmaf(x0, wa.w, bb.w)));
            float r0 = __builtin_amdgcn_rcpf(__expf(pre0) + 1.f);
            float r1 = __builtin_amdgcn_rcpf(__expf(pre1) + 1.f);
            float r2 = __builtin_amdgcn_rcpf(__expf(pre2) + 1.f);
            float r3 = __builtin_amdgcn_rcpf(__expf(pre3) + 1.f);
            acc = wr.x * r0;
            acc = fmaf(wr.y, r1, acc);
            acc = fmaf(wr.z, r2, acc);
            acc = fmaf(wr.w, r3, acc);
        }
        #pragma unroll
        for (int off = 32; off; off >>= 1) acc += __shfl_xor(acc, off);
        if (lane == 0) part[w][r] = sw - 2.f * acc;
    }
    __syncthreads();

    if (t < 32)
        out[(size_t)blockIdx.x * 32 + t] =
            b2r[0] + part[0][t] + part[1][t] + part[2][t] + part[3][t];
}

// ---------------------------------------------------------------------------
extern "C" void kernel_launch(void* const* d_in, const int* in_sizes, int n_in,
                              void* d_out, int out_size, void* d_ws, size_t ws_size,
                              hipStream_t stream)
{
    const float* input = (const float*)d_in[0];
    const float* eq    = (const float*)d_in[1];
    const float* W1    = (const float*)d_in[2];
    const float* b1    = (const float*)d_in[3];
    const float* W2    = (const float*)d_in[4];
    const float* b2    = (const float*)d_in[5];
    const float* q[4][5];
    for (int i = 0; i < 4; ++i)
        for (int k = 0; k < 5; ++k)
            q[i][k] = (const float*)d_in[6 + 5 * i + k];

    float* ws  = (float*)d_ws;
    float* w2r = ws;         // 1024
    float* b2r = ws + 1024;  // 1
    float* out = (float*)d_out;

    hipLaunchKernelGGL(k_front, dim3(256), dim3(256), 0, stream,
        eq,
        q[0][0], q[0][1], q[0][2], q[0][3], q[0][4],
        q[1][0], q[1][1], q[1][2], q[1][3], q[1][4],
        q[2][0], q[2][1], q[2][2], q[2][3], q[2][4],
        q[3][0], q[3][1], q[3][2], q[3][3], q[3][4],
        b2, W2, w2r, b2r);

    hipLaunchKernelGGL(k_out, dim3(1024), dim3(256), 0, stream,
        input, W1, b1, w2r, b2r, out);
}